// Round 3
// baseline (577.513 us; speedup 1.0000x reference)
//
#include <hip/hip_runtime.h>
#include <math.h>

// Problem constants (fixed by reference setup_inputs)
#define NN  50000
#define EE  400000
#define DD  64
#define HH  4
#define HC  256      // H * C
#define EDD 16

__device__ __forceinline__ float gelu_exact(float x) {
    return 0.5f * x * (1.0f + erff(x * 0.70710678118654752440f));
}
// fast exp via v_exp_f32: exp(x)=2^(x*log2e). exp2(-inf)=0 preserved.
__device__ __forceinline__ float fast_exp(float x) {
    return __builtin_amdgcn_exp2f(x * 1.44269504088896340736f);
}

// ---------- fills ----------
__global__ void fill_u32(unsigned* __restrict__ p, unsigned v, int n) {
    int i = blockIdx.x * blockDim.x + threadIdx.x;
    int s = gridDim.x * blockDim.x;
    for (; i < n; i += s) p[i] = v;
}

// ---------- CSR build ----------
__global__ void hist_k(const int* __restrict__ ei, int* __restrict__ deg) {
    int e = blockIdx.x * 256 + threadIdx.x;
    if (e < EE) atomicAdd(&deg[ei[EE + e]], 1);
}
__global__ void scan1_k(const int* __restrict__ deg, int* __restrict__ rowptr,
                        int* __restrict__ bsum) {
    __shared__ int s[256];
    int t = threadIdx.x, i = blockIdx.x * 256 + t;
    int v = (i < NN) ? deg[i] : 0;
    s[t] = v; __syncthreads();
    for (int o = 1; o < 256; o <<= 1) {
        int u = (t >= o) ? s[t - o] : 0;
        __syncthreads();
        s[t] += u;
        __syncthreads();
    }
    if (i < NN) rowptr[i] = s[t] - v;
    if (t == 255) bsum[blockIdx.x] = s[255];
}
__global__ void scan2_k(int* __restrict__ bsum, int nb) {
    __shared__ int s[256];
    int t = threadIdx.x;
    int v = (t < nb) ? bsum[t] : 0;
    s[t] = v; __syncthreads();
    for (int o = 1; o < 256; o <<= 1) {
        int u = (t >= o) ? s[t - o] : 0;
        __syncthreads();
        s[t] += u;
        __syncthreads();
    }
    if (t < nb) bsum[t] = s[t] - v;
}
__global__ void scan3_k(int* __restrict__ rowptr, const int* __restrict__ bsum,
                        int* __restrict__ cursor) {
    int i = blockIdx.x * 256 + threadIdx.x;
    if (i < NN) {
        int r = rowptr[i] + bsum[blockIdx.x];
        rowptr[i] = r;
        cursor[i] = r;
    }
    if (i == 0) rowptr[NN] = EE;
}
// scatter srcs AND edge_attr into CSR order
__global__ void scatter_k(const int* __restrict__ ei, int* __restrict__ cursor,
                          const float* __restrict__ ea,
                          int* __restrict__ srcs, float* __restrict__ ea_s) {
    int e = blockIdx.x * 256 + threadIdx.x;
    if (e >= EE) return;
    int dst = ei[EE + e];
    int pos = atomicAdd(&cursor[dst], 1);
    srcs[pos] = ei[e];
    const float4* s4 = (const float4*)(ea + (long)e * EDD);
    float4* d4 = (float4*)(ea_s + (long)pos * EDD);
    d4[0] = s4[0]; d4[1] = s4[1]; d4[2] = s4[2]; d4[3] = s4[3];
}

// wave -> node-range precompute: one thread per wave does the binary search
// (latency hidden across 16K parallel threads instead of serial per-wave).
__global__ void wrange_k(const int* __restrict__ rowptr, int* __restrict__ wstart,
                         int nw, int cpe) {
    int w = blockIdx.x * 256 + threadIdx.x;
    if (w > nw) return;
    if (w == nw) { wstart[nw] = NN; return; }
    const int lo = w * cpe;
    int l = 0, r = NN;
    while (l < r) { int m = (l + r) >> 1; if (rowptr[m] >= lo) r = m; else l = m + 1; }
    wstart[w] = l;
}

// ---------- node GEMM (dual): Y{l,r}[N,256] = X[N,64] @ W{l,r}[64,256] + b{l,r} ----------
__global__ __launch_bounds__(256) void gemm_node2(
    const float* __restrict__ X,
    const float* __restrict__ Wl, const float* __restrict__ bl,
    const float* __restrict__ Wr, const float* __restrict__ br,
    float* __restrict__ Yl, float* __restrict__ Yr)
{
    const int col  = threadIdx.x;
    const int base = blockIdx.x * 32;
    const float* __restrict__ W = blockIdx.y ? Wr : Wl;
    const float* __restrict__ b = blockIdx.y ? br : bl;
    float* __restrict__ Y       = blockIdx.y ? Yr : Yl;

    float wk[64];
#pragma unroll
    for (int k = 0; k < 64; k++) wk[k] = W[k * 256 + col];
    const float bb = b[col];

#pragma unroll 2
    for (int r = 0; r < 32; r++) {
        const int row = base + r;
        const int rr  = (row < NN) ? row : (NN - 1);
        const float4* __restrict__ x4 = (const float4*)(X + (long)rr * 64);
        float a0 = 0.f, a1 = 0.f, a2 = 0.f, a3 = 0.f;
#pragma unroll
        for (int k4 = 0; k4 < 16; k4++) {
            const float4 xv = x4[k4];
            a0 = fmaf(xv.x, wk[k4 * 4],     a0);
            a1 = fmaf(xv.y, wk[k4 * 4 + 1], a1);
            a2 = fmaf(xv.z, wk[k4 * 4 + 2], a2);
            a3 = fmaf(xv.w, wk[k4 * 4 + 3], a3);
        }
        if (row < NN) Y[(long)row * 256 + col] = (a0 + a1) + (a2 + a3) + bb;
    }
}

// ---------- fused: edge logits + softmax (no-max) + aggregation + LN/GELU ----------
// One wave per edge-balanced contiguous node range (range precomputed by
// wrange_k). Edge loop unrolled x2 with two independent chains. All scalar
// control values (rowptr, first-edge srcs) are software-pipelined one node
// ahead so no dependent scalar load sits on the critical path.
// srcs padded by 16 ints, rowptr padded by 3 -> prefetches need no guards.
// NOTE (R9): no full vector-data pipelining across iterations — spills.
__global__ __launch_bounds__(256, 4) void fused_edge_node_k(
    const int* __restrict__ wstart,
    const int* __restrict__ rowptr, const int* __restrict__ srcs,
    const float* __restrict__ ea_s,
    const float* __restrict__ We, const float* __restrict__ att,
    const float* __restrict__ xl, const float* __restrict__ xr,
    const float* __restrict__ bias, const float* __restrict__ lng,
    const float* __restrict__ lnb, const float* __restrict__ identity,
    float* __restrict__ x1out, float* __restrict__ outp, int mode)
{
    const int lane = threadIdx.x & 63;
    const int h    = lane >> 4;
    const int jj   = lane & 15;
    const int gc   = (h << 6) + (jj << 2);
    const int cb   = jj << 2;

    // per-lane We columns (64 VGPRs), loaded once per wave
    float wreg[EDD][4];
#pragma unroll
    for (int k = 0; k < EDD; k++) {
        const float4 w4 = *(const float4*)(We + k * HC + gc);
        wreg[k][0] = w4.x; wreg[k][1] = w4.y; wreg[k][2] = w4.z; wreg[k][3] = w4.w;
    }
#pragma unroll
    for (int k = 0; k < EDD; k++)
#pragma unroll
        for (int j = 0; j < 4; j++) asm volatile("" : "+v"(wreg[k][j]));

    const float4 a4 = *(const float4*)(att + gc);

    const int wid  = blockIdx.x * 4 + (threadIdx.x >> 6);
    const int nbeg = __builtin_amdgcn_readfirstlane(wstart[wid]);
    const int nend = __builtin_amdgcn_readfirstlane(wstart[wid + 1]);

    // scalar pipeline: p0v/p1v = rowptr for current node, sAn/sBn = first
    // two srcs of current node; all loaded one iteration ahead.
    int p0v = rowptr[nbeg];
    int p1v = rowptr[nbeg + 1];
    int sAn = srcs[p0v];
    int sBn = srcs[p0v + 1];

    for (int n = nbeg; n < nend; n++) {
        const int p0 = __builtin_amdgcn_readfirstlane(p0v);
        const int p1 = __builtin_amdgcn_readfirstlane(p1v);
        // prefetch next node's scalars (latency covered by this node's body)
        p0v = p1;
        p1v = rowptr[(n + 2 <= NN) ? (n + 2) : NN];
        int sA = sAn, sB = sBn;
        sAn = srcs[p1];
        sBn = srcs[p1 + 1];

        const float4 xrv = *(const float4*)(xr + (long)n * HC + gc);

        float dsum = 0.f;
        float ac0 = 0.f, ac1 = 0.f, ac2 = 0.f, ac3 = 0.f;

        int p = p0;
        for (; p + 1 < p1; p += 2) {
            const int srcA = __builtin_amdgcn_readfirstlane(sA);
            const int srcB = __builtin_amdgcn_readfirstlane(sB);
            sA = srcs[p + 2];                       // prefetch next pair
            sB = srcs[p + 3];

            const float4 xlvA = *(const float4*)(xl + (long)srcA * HC + gc);
            const float4 xlvB = *(const float4*)(xl + (long)srcB * HC + gc);

            const float4* __restrict__ e4 = (const float4*)(ea_s + (long)p * EDD);
            float eavA[EDD], eavB[EDD];
            *(float4*)&eavA[0]  = e4[0];
            *(float4*)&eavA[4]  = e4[1];
            *(float4*)&eavA[8]  = e4[2];
            *(float4*)&eavA[12] = e4[3];
            *(float4*)&eavB[0]  = e4[4];
            *(float4*)&eavB[4]  = e4[5];
            *(float4*)&eavB[8]  = e4[6];
            *(float4*)&eavB[12] = e4[7];

            float eA0 = 0.f, eA1 = 0.f, eA2 = 0.f, eA3 = 0.f;
            float eB0 = 0.f, eB1 = 0.f, eB2 = 0.f, eB3 = 0.f;
#pragma unroll
            for (int k = 0; k < EDD; k++) {
                eA0 = fmaf(eavA[k], wreg[k][0], eA0);
                eA1 = fmaf(eavA[k], wreg[k][1], eA1);
                eA2 = fmaf(eavA[k], wreg[k][2], eA2);
                eA3 = fmaf(eavA[k], wreg[k][3], eA3);
                eB0 = fmaf(eavB[k], wreg[k][0], eB0);
                eB1 = fmaf(eavB[k], wreg[k][1], eB1);
                eB2 = fmaf(eavB[k], wreg[k][2], eB2);
                eB3 = fmaf(eavB[k], wreg[k][3], eB3);
            }
            float sA0 = xlvA.x + xrv.x + eA0;
            float sA1 = xlvA.y + xrv.y + eA1;
            float sA2 = xlvA.z + xrv.z + eA2;
            float sA3 = xlvA.w + xrv.w + eA3;
            float sB0 = xlvB.x + xrv.x + eB0;
            float sB1 = xlvB.y + xrv.y + eB1;
            float sB2 = xlvB.z + xrv.z + eB2;
            float sB3 = xlvB.w + xrv.w + eB3;
            sA0 = (sA0 > 0.f) ? sA0 : 0.2f * sA0;
            sA1 = (sA1 > 0.f) ? sA1 : 0.2f * sA1;
            sA2 = (sA2 > 0.f) ? sA2 : 0.2f * sA2;
            sA3 = (sA3 > 0.f) ? sA3 : 0.2f * sA3;
            sB0 = (sB0 > 0.f) ? sB0 : 0.2f * sB0;
            sB1 = (sB1 > 0.f) ? sB1 : 0.2f * sB1;
            sB2 = (sB2 > 0.f) ? sB2 : 0.2f * sB2;
            sB3 = (sB3 > 0.f) ? sB3 : 0.2f * sB3;
            float pA = fmaf(sA0, a4.x, fmaf(sA1, a4.y, fmaf(sA2, a4.z, sA3 * a4.w)));
            float pB = fmaf(sB0, a4.x, fmaf(sB1, a4.y, fmaf(sB2, a4.z, sB3 * a4.w)));
            // two independent butterflies — interleave, latency overlaps
            pA += __shfl_xor(pA, 1, 64);
            pB += __shfl_xor(pB, 1, 64);
            pA += __shfl_xor(pA, 2, 64);
            pB += __shfl_xor(pB, 2, 64);
            pA += __shfl_xor(pA, 4, 64);
            pB += __shfl_xor(pB, 4, 64);
            pA += __shfl_xor(pA, 8, 64);
            pB += __shfl_xor(pB, 8, 64);

            const float wA = fast_exp(pA);
            const float wB = fast_exp(pB);
            dsum += (wA + wB);
            ac0 = fmaf(wA, xlvA.x, ac0);
            ac1 = fmaf(wA, xlvA.y, ac1);
            ac2 = fmaf(wA, xlvA.z, ac2);
            ac3 = fmaf(wA, xlvA.w, ac3);
            ac0 = fmaf(wB, xlvB.x, ac0);
            ac1 = fmaf(wB, xlvB.y, ac1);
            ac2 = fmaf(wB, xlvB.z, ac2);
            ac3 = fmaf(wB, xlvB.w, ac3);
        }

        if (p < p1) {   // odd tail
            const int src = __builtin_amdgcn_readfirstlane(sA);
            const float4 xlv = *(const float4*)(xl + (long)src * HC + gc);
            const float4* __restrict__ e4 = (const float4*)(ea_s + (long)p * EDD);
            float eav[EDD];
            *(float4*)&eav[0]  = e4[0];
            *(float4*)&eav[4]  = e4[1];
            *(float4*)&eav[8]  = e4[2];
            *(float4*)&eav[12] = e4[3];
            float ez0 = 0.f, ez1 = 0.f, ez2 = 0.f, ez3 = 0.f;
#pragma unroll
            for (int k = 0; k < EDD; k++) {
                ez0 = fmaf(eav[k], wreg[k][0], ez0);
                ez1 = fmaf(eav[k], wreg[k][1], ez1);
                ez2 = fmaf(eav[k], wreg[k][2], ez2);
                ez3 = fmaf(eav[k], wreg[k][3], ez3);
            }
            float s0 = xlv.x + xrv.x + ez0;
            float s1 = xlv.y + xrv.y + ez1;
            float s2 = xlv.z + xrv.z + ez2;
            float s3 = xlv.w + xrv.w + ez3;
            s0 = (s0 > 0.f) ? s0 : 0.2f * s0;
            s1 = (s1 > 0.f) ? s1 : 0.2f * s1;
            s2 = (s2 > 0.f) ? s2 : 0.2f * s2;
            s3 = (s3 > 0.f) ? s3 : 0.2f * s3;
            float part = fmaf(s0, a4.x, fmaf(s1, a4.y, fmaf(s2, a4.z, s3 * a4.w)));
            part += __shfl_xor(part, 1, 64);
            part += __shfl_xor(part, 2, 64);
            part += __shfl_xor(part, 4, 64);
            part += __shfl_xor(part, 8, 64);
            const float w = fast_exp(part);
            dsum += w;
            ac0 = fmaf(w, xlv.x, ac0);
            ac1 = fmaf(w, xlv.y, ac1);
            ac2 = fmaf(w, xlv.z, ac2);
            ac3 = fmaf(w, xlv.w, ac3);
        }

        const float inv = 1.0f / (dsum + 1e-16f);
        float v0 = ac0 * inv, v1 = ac1 * inv, v2 = ac2 * inv, v3 = ac3 * inv;

        // head mean across the 4 groups
        v0 += __shfl_xor(v0, 16, 64); v0 += __shfl_xor(v0, 32, 64);
        v1 += __shfl_xor(v1, 16, 64); v1 += __shfl_xor(v1, 32, 64);
        v2 += __shfl_xor(v2, 16, 64); v2 += __shfl_xor(v2, 32, 64);
        v3 += __shfl_xor(v3, 16, 64); v3 += __shfl_xor(v3, 32, 64);

        if (lane < 16) {   // group 0 finishes LN + GELU + store
            const float4 b4 = *(const float4*)(bias + cb);
            v0 = v0 * 0.25f + b4.x;
            v1 = v1 * 0.25f + b4.y;
            v2 = v2 * 0.25f + b4.z;
            v3 = v3 * 0.25f + b4.w;

            float s = (v0 + v1) + (v2 + v3);
            s += __shfl_xor(s, 1, 64); s += __shfl_xor(s, 2, 64);
            s += __shfl_xor(s, 4, 64); s += __shfl_xor(s, 8, 64);
            const float mu = s * (1.0f / 64.0f);
            const float d0 = v0 - mu, d1 = v1 - mu, d2 = v2 - mu, d3 = v3 - mu;
            float q = (d0 * d0 + d1 * d1) + (d2 * d2 + d3 * d3);
            q += __shfl_xor(q, 1, 64); q += __shfl_xor(q, 2, 64);
            q += __shfl_xor(q, 4, 64); q += __shfl_xor(q, 8, 64);
            const float rs = rsqrtf(q * (1.0f / 64.0f) + 1e-5f);

            const float4 g4 = *(const float4*)(lng + cb);
            const float4 c4 = *(const float4*)(lnb + cb);
            float y0 = d0 * rs * g4.x + c4.x;
            float y1 = d1 * rs * g4.y + c4.y;
            float y2 = d2 * rs * g4.z + c4.z;
            float y3 = d3 * rs * g4.w + c4.w;

            if (mode == 0) {
                float4 o;
                o.x = gelu_exact(y0); o.y = gelu_exact(y1);
                o.z = gelu_exact(y2); o.w = gelu_exact(y3);
                *(float4*)(x1out + (long)n * DD + cb) = o;
            } else {
                const float4 id = *(const float4*)(identity + (long)n * DD + cb);
                float4 o;
                o.x = gelu_exact(y0 + id.x); o.y = gelu_exact(y1 + id.y);
                o.z = gelu_exact(y2 + id.z); o.w = gelu_exact(y3 + id.w);
                *(float4*)(outp + (long)n * DD + cb) = o;
            }
        }
    }
}

// ---------- launch ----------
extern "C" void kernel_launch(void* const* d_in, const int* in_sizes, int n_in,
                              void* d_out, int out_size, void* d_ws, size_t ws_size,
                              hipStream_t stream) {
    (void)in_sizes; (void)n_in; (void)out_size; (void)ws_size;

    const float* h     = (const float*)d_in[0];
    const int*   ei    = (const int*)d_in[1];
    const float* ea    = (const float*)d_in[2];
    const float* g1Wl  = (const float*)d_in[3];
    const float* g1bl  = (const float*)d_in[4];
    const float* g1Wr  = (const float*)d_in[5];
    const float* g1br  = (const float*)d_in[6];
    const float* g1We  = (const float*)d_in[7];
    const float* g1att = (const float*)d_in[8];
    const float* g1bias= (const float*)d_in[9];
    const float* ln1g  = (const float*)d_in[10];
    const float* ln1b  = (const float*)d_in[11];
    const float* g2Wl  = (const float*)d_in[12];
    const float* g2bl  = (const float*)d_in[13];
    const float* g2Wr  = (const float*)d_in[14];
    const float* g2br  = (const float*)d_in[15];
    const float* g2We  = (const float*)d_in[16];
    const float* g2att = (const float*)d_in[17];
    const float* g2bias= (const float*)d_in[18];
    const float* ln2g  = (const float*)d_in[19];
    const float* ln2b  = (const float*)d_in[20];

    float* out = (float*)d_out;

    const int FUSED_BLOCKS = 4096;              // 16384 waves, ~25 edges each
    const int NW  = FUSED_BLOCKS * 4;
    const int CPE = (EE + NW - 1) / NW;

    // workspace layout (4-byte units)
    float* ws = (float*)d_ws;
    size_t o = 0;
    float* xl     = ws + o;         o += 12800000;   // N*256
    float* xr     = ws + o;         o += 12800000;   // N*256
    float* x1     = ws + o;         o += 3200000;    // N*64
    int*   rowptr = (int*)(ws + o); o += 50004;      // N+1 (+3 pad)
    int*   deg    = (int*)(ws + o); o += 50000;
    int*   cursor = (int*)(ws + o); o += 50000;
    int*   bsum   = (int*)(ws + o); o += 256;
    int*   srcs   = (int*)(ws + o); o += 400016;     // E + 16 pad (prefetch)
    int*   wstart = (int*)(ws + o); o += NW + 8;     // wave node ranges
    float* ea_s   = ws + o;         o += 6400000;    // E*16, CSR-sorted

    const int GEMM_BLOCKS  = (NN + 31) / 32;    // 1563
    const int SCAN_BLOCKS  = (NN + 255) / 256;  // 196
    const int EDGE_BLOCKS  = (EE + 255) / 256;  // 1563
    const int WR_BLOCKS    = (NW + 1 + 255) / 256;

    // ----- CSR build (once; graph identical for both layers) -----
    fill_u32<<<256, 256, 0, stream>>>((unsigned*)deg, 0u, NN);
    hist_k<<<EDGE_BLOCKS, 256, 0, stream>>>(ei, deg);
    scan1_k<<<SCAN_BLOCKS, 256, 0, stream>>>(deg, rowptr, bsum);
    scan2_k<<<1, 256, 0, stream>>>(bsum, SCAN_BLOCKS);
    scan3_k<<<SCAN_BLOCKS, 256, 0, stream>>>(rowptr, bsum, cursor);
    wrange_k<<<WR_BLOCKS, 256, 0, stream>>>(rowptr, wstart, NW, CPE);
    scatter_k<<<EDGE_BLOCKS, 256, 0, stream>>>(ei, cursor, ea, srcs, ea_s);

    // ----- layer 1 -----
    gemm_node2<<<dim3(GEMM_BLOCKS, 2), 256, 0, stream>>>(h, g1Wl, g1bl, g1Wr, g1br, xl, xr);
    fused_edge_node_k<<<FUSED_BLOCKS, 256, 0, stream>>>(wstart, rowptr, srcs, ea_s,
                                                        g1We, g1att, xl, xr,
                                                        g1bias, ln1g, ln1b,
                                                        h, x1, out, 0);

    // ----- layer 2 -----
    gemm_node2<<<dim3(GEMM_BLOCKS, 2), 256, 0, stream>>>(x1, g2Wl, g2bl, g2Wr, g2br, xl, xr);
    fused_edge_node_k<<<FUSED_BLOCKS, 256, 0, stream>>>(wstart, rowptr, srcs, ea_s,
                                                        g2We, g2att, xl, xr,
                                                        g2bias, ln2g, ln2b,
                                                        h, x1, out, 1);
}

// Round 4
// 495.526 us; speedup vs baseline: 1.1655x; 1.1655x over previous
//
#include <hip/hip_runtime.h>
#include <math.h>

// Problem constants (fixed by reference setup_inputs)
#define NN  50000
#define EE  400000
#define DD  64
#define HH  4
#define HC  256      // H * C
#define EDD 16

__device__ __forceinline__ float gelu_exact(float x) {
    return 0.5f * x * (1.0f + erff(x * 0.70710678118654752440f));
}
// fast exp via v_exp_f32: exp(x)=2^(x*log2e). exp2(-inf)=0 preserved.
__device__ __forceinline__ float fast_exp(float x) {
    return __builtin_amdgcn_exp2f(x * 1.44269504088896340736f);
}

// ---------- fills ----------
__global__ void fill_u32(unsigned* __restrict__ p, unsigned v, int n) {
    int i = blockIdx.x * blockDim.x + threadIdx.x;
    int s = gridDim.x * blockDim.x;
    for (; i < n; i += s) p[i] = v;
}

// ---------- CSR build ----------
__global__ void hist_k(const int* __restrict__ ei, int* __restrict__ deg) {
    int e = blockIdx.x * 256 + threadIdx.x;
    if (e < EE) atomicAdd(&deg[ei[EE + e]], 1);
}
__global__ void scan1_k(const int* __restrict__ deg, int* __restrict__ rowptr,
                        int* __restrict__ bsum) {
    __shared__ int s[256];
    int t = threadIdx.x, i = blockIdx.x * 256 + t;
    int v = (i < NN) ? deg[i] : 0;
    s[t] = v; __syncthreads();
    for (int o = 1; o < 256; o <<= 1) {
        int u = (t >= o) ? s[t - o] : 0;
        __syncthreads();
        s[t] += u;
        __syncthreads();
    }
    if (i < NN) rowptr[i] = s[t] - v;
    if (t == 255) bsum[blockIdx.x] = s[255];
}
__global__ void scan2_k(int* __restrict__ bsum, int nb) {
    __shared__ int s[256];
    int t = threadIdx.x;
    int v = (t < nb) ? bsum[t] : 0;
    s[t] = v; __syncthreads();
    for (int o = 1; o < 256; o <<= 1) {
        int u = (t >= o) ? s[t - o] : 0;
        __syncthreads();
        s[t] += u;
        __syncthreads();
    }
    if (t < nb) bsum[t] = s[t] - v;
}
__global__ void scan3_k(int* __restrict__ rowptr, const int* __restrict__ bsum,
                        int* __restrict__ cursor) {
    int i = blockIdx.x * 256 + threadIdx.x;
    if (i < NN) {
        int r = rowptr[i] + bsum[blockIdx.x];
        rowptr[i] = r;
        cursor[i] = r;
    }
    if (i == 0) rowptr[NN] = EE;
}
// scatter srcs AND edge_attr into CSR order
__global__ void scatter_k(const int* __restrict__ ei, int* __restrict__ cursor,
                          const float* __restrict__ ea,
                          int* __restrict__ srcs, float* __restrict__ ea_s) {
    int e = blockIdx.x * 256 + threadIdx.x;
    if (e >= EE) return;
    int dst = ei[EE + e];
    int pos = atomicAdd(&cursor[dst], 1);
    srcs[pos] = ei[e];
    const float4* s4 = (const float4*)(ea + (long)e * EDD);
    float4* d4 = (float4*)(ea_s + (long)pos * EDD);
    d4[0] = s4[0]; d4[1] = s4[1]; d4[2] = s4[2]; d4[3] = s4[3];
}

// wave -> node-range precompute: one thread per wave does the binary search
__global__ void wrange_k(const int* __restrict__ rowptr, int* __restrict__ wstart,
                         int nw, int cpe) {
    int w = blockIdx.x * 256 + threadIdx.x;
    if (w > nw) return;
    if (w == nw) { wstart[nw] = NN; return; }
    const int lo = w * cpe;
    int l = 0, r = NN;
    while (l < r) { int m = (l + r) >> 1; if (rowptr[m] >= lo) r = m; else l = m + 1; }
    wstart[w] = l;
}

// ---------- node GEMM (merged l+r): Y{l,r}[N,256] = X[N,64] @ W{l,r} + b{l,r} ----------
// R3 post-mortem: per-row X loads are wave-uniform -> compiler emits s_load
// (SMEM), whose lgkmcnt waits are all-or-nothing -> 19% VALUBusy. Fix:
// stage the X tile in LDS via per-lane coalesced vector loads (vmcnt path),
// compute from ds_read_b128 broadcasts (fine-grained lgkmcnt partial waits).
// Both Wl and Wr columns live in registers so each ds_read feeds 2 FMA sets
// (FMA:LDS cycle ratio ~256:192 per row), and X is staged once for both.
__global__ __launch_bounds__(256) void gemm_node_lr(
    const float* __restrict__ X,
    const float* __restrict__ Wl, const float* __restrict__ bl,
    const float* __restrict__ Wr, const float* __restrict__ br,
    float* __restrict__ Yl, float* __restrict__ Yr)
{
    __shared__ float xs[32][64];      // 8 KB tile
    const int tid  = threadIdx.x;
    const int col  = tid;
    const int base = blockIdx.x * 32;

    // stage X tile: 512 float4, 256 threads -> 2 each (coalesced, per-lane)
#pragma unroll
    for (int i = 0; i < 2; i++) {
        const int f   = tid + i * 256;         // float4 index 0..511
        const int r   = f >> 4;
        const int row = base + r;
        const int rr  = (row < NN) ? row : (NN - 1);
        const float4 v = *(const float4*)(X + (long)rr * 64 + ((f & 15) << 2));
        *(float4*)&xs[r][(f & 15) << 2] = v;
    }

    // both W columns into registers (128 VGPRs)
    float wl[64], wr[64];
#pragma unroll
    for (int k = 0; k < 64; k++) wl[k] = Wl[k * 256 + col];
#pragma unroll
    for (int k = 0; k < 64; k++) wr[k] = Wr[k * 256 + col];
    const float bbl = bl[col];
    const float bbr = br[col];

    __syncthreads();

#pragma unroll 2
    for (int r = 0; r < 32; r++) {
        const int row = base + r;
        float l0 = 0.f, l1 = 0.f, l2 = 0.f, l3 = 0.f;
        float r0 = 0.f, r1 = 0.f, r2 = 0.f, r3 = 0.f;
#pragma unroll
        for (int k4 = 0; k4 < 16; k4++) {
            const float4 xv = *(const float4*)&xs[r][k4 << 2];   // broadcast read
            l0 = fmaf(xv.x, wl[k4 * 4],     l0);
            l1 = fmaf(xv.y, wl[k4 * 4 + 1], l1);
            l2 = fmaf(xv.z, wl[k4 * 4 + 2], l2);
            l3 = fmaf(xv.w, wl[k4 * 4 + 3], l3);
            r0 = fmaf(xv.x, wr[k4 * 4],     r0);
            r1 = fmaf(xv.y, wr[k4 * 4 + 1], r1);
            r2 = fmaf(xv.z, wr[k4 * 4 + 2], r2);
            r3 = fmaf(xv.w, wr[k4 * 4 + 3], r3);
        }
        if (row < NN) {
            Yl[(long)row * 256 + col] = (l0 + l1) + (l2 + l3) + bbl;
            Yr[(long)row * 256 + col] = (r0 + r1) + (r2 + r3) + bbr;
        }
    }
}

// ---------- fused: edge logits + softmax (no-max) + aggregation + LN/GELU ----------
// One wave per edge-balanced contiguous node range (range precomputed by
// wrange_k). Edge loop unrolled x2 with two independent chains. All scalar
// control values (rowptr, first-edge srcs) are software-pipelined one node
// ahead so no dependent scalar load sits on the critical path.
// srcs padded by 16 ints, rowptr padded by 3 -> prefetches need no guards.
// NOTE (R9): no full vector-data pipelining across iterations — spills.
__global__ __launch_bounds__(256, 4) void fused_edge_node_k(
    const int* __restrict__ wstart,
    const int* __restrict__ rowptr, const int* __restrict__ srcs,
    const float* __restrict__ ea_s,
    const float* __restrict__ We, const float* __restrict__ att,
    const float* __restrict__ xl, const float* __restrict__ xr,
    const float* __restrict__ bias, const float* __restrict__ lng,
    const float* __restrict__ lnb, const float* __restrict__ identity,
    float* __restrict__ x1out, float* __restrict__ outp, int mode)
{
    const int lane = threadIdx.x & 63;
    const int h    = lane >> 4;
    const int jj   = lane & 15;
    const int gc   = (h << 6) + (jj << 2);
    const int cb   = jj << 2;

    // per-lane We columns (64 VGPRs), loaded once per wave
    float wreg[EDD][4];
#pragma unroll
    for (int k = 0; k < EDD; k++) {
        const float4 w4 = *(const float4*)(We + k * HC + gc);
        wreg[k][0] = w4.x; wreg[k][1] = w4.y; wreg[k][2] = w4.z; wreg[k][3] = w4.w;
    }
#pragma unroll
    for (int k = 0; k < EDD; k++)
#pragma unroll
        for (int j = 0; j < 4; j++) asm volatile("" : "+v"(wreg[k][j]));

    const float4 a4 = *(const float4*)(att + gc);

    const int wid  = blockIdx.x * 4 + (threadIdx.x >> 6);
    const int nbeg = __builtin_amdgcn_readfirstlane(wstart[wid]);
    const int nend = __builtin_amdgcn_readfirstlane(wstart[wid + 1]);

    // scalar pipeline: p0v/p1v = rowptr for current node, sAn/sBn = first
    // two srcs of current node; all loaded one iteration ahead.
    int p0v = rowptr[nbeg];
    int p1v = rowptr[nbeg + 1];
    int sAn = srcs[p0v];
    int sBn = srcs[p0v + 1];

    for (int n = nbeg; n < nend; n++) {
        const int p0 = __builtin_amdgcn_readfirstlane(p0v);
        const int p1 = __builtin_amdgcn_readfirstlane(p1v);
        // prefetch next node's scalars (latency covered by this node's body)
        p0v = p1;
        p1v = rowptr[(n + 2 <= NN) ? (n + 2) : NN];
        int sA = sAn, sB = sBn;
        sAn = srcs[p1];
        sBn = srcs[p1 + 1];

        const float4 xrv = *(const float4*)(xr + (long)n * HC + gc);

        float dsum = 0.f;
        float ac0 = 0.f, ac1 = 0.f, ac2 = 0.f, ac3 = 0.f;

        int p = p0;
        for (; p + 1 < p1; p += 2) {
            const int srcA = __builtin_amdgcn_readfirstlane(sA);
            const int srcB = __builtin_amdgcn_readfirstlane(sB);
            sA = srcs[p + 2];                       // prefetch next pair
            sB = srcs[p + 3];

            const float4 xlvA = *(const float4*)(xl + (long)srcA * HC + gc);
            const float4 xlvB = *(const float4*)(xl + (long)srcB * HC + gc);

            const float4* __restrict__ e4 = (const float4*)(ea_s + (long)p * EDD);
            float eavA[EDD], eavB[EDD];
            *(float4*)&eavA[0]  = e4[0];
            *(float4*)&eavA[4]  = e4[1];
            *(float4*)&eavA[8]  = e4[2];
            *(float4*)&eavA[12] = e4[3];
            *(float4*)&eavB[0]  = e4[4];
            *(float4*)&eavB[4]  = e4[5];
            *(float4*)&eavB[8]  = e4[6];
            *(float4*)&eavB[12] = e4[7];

            float eA0 = 0.f, eA1 = 0.f, eA2 = 0.f, eA3 = 0.f;
            float eB0 = 0.f, eB1 = 0.f, eB2 = 0.f, eB3 = 0.f;
#pragma unroll
            for (int k = 0; k < EDD; k++) {
                eA0 = fmaf(eavA[k], wreg[k][0], eA0);
                eA1 = fmaf(eavA[k], wreg[k][1], eA1);
                eA2 = fmaf(eavA[k], wreg[k][2], eA2);
                eA3 = fmaf(eavA[k], wreg[k][3], eA3);
                eB0 = fmaf(eavB[k], wreg[k][0], eB0);
                eB1 = fmaf(eavB[k], wreg[k][1], eB1);
                eB2 = fmaf(eavB[k], wreg[k][2], eB2);
                eB3 = fmaf(eavB[k], wreg[k][3], eB3);
            }
            float sA0 = xlvA.x + xrv.x + eA0;
            float sA1 = xlvA.y + xrv.y + eA1;
            float sA2 = xlvA.z + xrv.z + eA2;
            float sA3 = xlvA.w + xrv.w + eA3;
            float sB0 = xlvB.x + xrv.x + eB0;
            float sB1 = xlvB.y + xrv.y + eB1;
            float sB2 = xlvB.z + xrv.z + eB2;
            float sB3 = xlvB.w + xrv.w + eB3;
            sA0 = (sA0 > 0.f) ? sA0 : 0.2f * sA0;
            sA1 = (sA1 > 0.f) ? sA1 : 0.2f * sA1;
            sA2 = (sA2 > 0.f) ? sA2 : 0.2f * sA2;
            sA3 = (sA3 > 0.f) ? sA3 : 0.2f * sA3;
            sB0 = (sB0 > 0.f) ? sB0 : 0.2f * sB0;
            sB1 = (sB1 > 0.f) ? sB1 : 0.2f * sB1;
            sB2 = (sB2 > 0.f) ? sB2 : 0.2f * sB2;
            sB3 = (sB3 > 0.f) ? sB3 : 0.2f * sB3;
            float pA = fmaf(sA0, a4.x, fmaf(sA1, a4.y, fmaf(sA2, a4.z, sA3 * a4.w)));
            float pB = fmaf(sB0, a4.x, fmaf(sB1, a4.y, fmaf(sB2, a4.z, sB3 * a4.w)));
            // two independent butterflies — interleave, latency overlaps
            pA += __shfl_xor(pA, 1, 64);
            pB += __shfl_xor(pB, 1, 64);
            pA += __shfl_xor(pA, 2, 64);
            pB += __shfl_xor(pB, 2, 64);
            pA += __shfl_xor(pA, 4, 64);
            pB += __shfl_xor(pB, 4, 64);
            pA += __shfl_xor(pA, 8, 64);
            pB += __shfl_xor(pB, 8, 64);

            const float wA = fast_exp(pA);
            const float wB = fast_exp(pB);
            dsum += (wA + wB);
            ac0 = fmaf(wA, xlvA.x, ac0);
            ac1 = fmaf(wA, xlvA.y, ac1);
            ac2 = fmaf(wA, xlvA.z, ac2);
            ac3 = fmaf(wA, xlvA.w, ac3);
            ac0 = fmaf(wB, xlvB.x, ac0);
            ac1 = fmaf(wB, xlvB.y, ac1);
            ac2 = fmaf(wB, xlvB.z, ac2);
            ac3 = fmaf(wB, xlvB.w, ac3);
        }

        if (p < p1) {   // odd tail
            const int src = __builtin_amdgcn_readfirstlane(sA);
            const float4 xlv = *(const float4*)(xl + (long)src * HC + gc);
            const float4* __restrict__ e4 = (const float4*)(ea_s + (long)p * EDD);
            float eav[EDD];
            *(float4*)&eav[0]  = e4[0];
            *(float4*)&eav[4]  = e4[1];
            *(float4*)&eav[8]  = e4[2];
            *(float4*)&eav[12] = e4[3];
            float ez0 = 0.f, ez1 = 0.f, ez2 = 0.f, ez3 = 0.f;
#pragma unroll
            for (int k = 0; k < EDD; k++) {
                ez0 = fmaf(eav[k], wreg[k][0], ez0);
                ez1 = fmaf(eav[k], wreg[k][1], ez1);
                ez2 = fmaf(eav[k], wreg[k][2], ez2);
                ez3 = fmaf(eav[k], wreg[k][3], ez3);
            }
            float s0 = xlv.x + xrv.x + ez0;
            float s1 = xlv.y + xrv.y + ez1;
            float s2 = xlv.z + xrv.z + ez2;
            float s3 = xlv.w + xrv.w + ez3;
            s0 = (s0 > 0.f) ? s0 : 0.2f * s0;
            s1 = (s1 > 0.f) ? s1 : 0.2f * s1;
            s2 = (s2 > 0.f) ? s2 : 0.2f * s2;
            s3 = (s3 > 0.f) ? s3 : 0.2f * s3;
            float part = fmaf(s0, a4.x, fmaf(s1, a4.y, fmaf(s2, a4.z, s3 * a4.w)));
            part += __shfl_xor(part, 1, 64);
            part += __shfl_xor(part, 2, 64);
            part += __shfl_xor(part, 4, 64);
            part += __shfl_xor(part, 8, 64);
            const float w = fast_exp(part);
            dsum += w;
            ac0 = fmaf(w, xlv.x, ac0);
            ac1 = fmaf(w, xlv.y, ac1);
            ac2 = fmaf(w, xlv.z, ac2);
            ac3 = fmaf(w, xlv.w, ac3);
        }

        const float inv = 1.0f / (dsum + 1e-16f);
        float v0 = ac0 * inv, v1 = ac1 * inv, v2 = ac2 * inv, v3 = ac3 * inv;

        // head mean across the 4 groups
        v0 += __shfl_xor(v0, 16, 64); v0 += __shfl_xor(v0, 32, 64);
        v1 += __shfl_xor(v1, 16, 64); v1 += __shfl_xor(v1, 32, 64);
        v2 += __shfl_xor(v2, 16, 64); v2 += __shfl_xor(v2, 32, 64);
        v3 += __shfl_xor(v3, 16, 64); v3 += __shfl_xor(v3, 32, 64);

        if (lane < 16) {   // group 0 finishes LN + GELU + store
            const float4 b4 = *(const float4*)(bias + cb);
            v0 = v0 * 0.25f + b4.x;
            v1 = v1 * 0.25f + b4.y;
            v2 = v2 * 0.25f + b4.z;
            v3 = v3 * 0.25f + b4.w;

            float s = (v0 + v1) + (v2 + v3);
            s += __shfl_xor(s, 1, 64); s += __shfl_xor(s, 2, 64);
            s += __shfl_xor(s, 4, 64); s += __shfl_xor(s, 8, 64);
            const float mu = s * (1.0f / 64.0f);
            const float d0 = v0 - mu, d1 = v1 - mu, d2 = v2 - mu, d3 = v3 - mu;
            float q = (d0 * d0 + d1 * d1) + (d2 * d2 + d3 * d3);
            q += __shfl_xor(q, 1, 64); q += __shfl_xor(q, 2, 64);
            q += __shfl_xor(q, 4, 64); q += __shfl_xor(q, 8, 64);
            const float rs = rsqrtf(q * (1.0f / 64.0f) + 1e-5f);

            const float4 g4 = *(const float4*)(lng + cb);
            const float4 c4 = *(const float4*)(lnb + cb);
            float y0 = d0 * rs * g4.x + c4.x;
            float y1 = d1 * rs * g4.y + c4.y;
            float y2 = d2 * rs * g4.z + c4.z;
            float y3 = d3 * rs * g4.w + c4.w;

            if (mode == 0) {
                float4 o;
                o.x = gelu_exact(y0); o.y = gelu_exact(y1);
                o.z = gelu_exact(y2); o.w = gelu_exact(y3);
                *(float4*)(x1out + (long)n * DD + cb) = o;
            } else {
                const float4 id = *(const float4*)(identity + (long)n * DD + cb);
                float4 o;
                o.x = gelu_exact(y0 + id.x); o.y = gelu_exact(y1 + id.y);
                o.z = gelu_exact(y2 + id.z); o.w = gelu_exact(y3 + id.w);
                *(float4*)(outp + (long)n * DD + cb) = o;
            }
        }
    }
}

// ---------- launch ----------
extern "C" void kernel_launch(void* const* d_in, const int* in_sizes, int n_in,
                              void* d_out, int out_size, void* d_ws, size_t ws_size,
                              hipStream_t stream) {
    (void)in_sizes; (void)n_in; (void)out_size; (void)ws_size;

    const float* h     = (const float*)d_in[0];
    const int*   ei    = (const int*)d_in[1];
    const float* ea    = (const float*)d_in[2];
    const float* g1Wl  = (const float*)d_in[3];
    const float* g1bl  = (const float*)d_in[4];
    const float* g1Wr  = (const float*)d_in[5];
    const float* g1br  = (const float*)d_in[6];
    const float* g1We  = (const float*)d_in[7];
    const float* g1att = (const float*)d_in[8];
    const float* g1bias= (const float*)d_in[9];
    const float* ln1g  = (const float*)d_in[10];
    const float* ln1b  = (const float*)d_in[11];
    const float* g2Wl  = (const float*)d_in[12];
    const float* g2bl  = (const float*)d_in[13];
    const float* g2Wr  = (const float*)d_in[14];
    const float* g2br  = (const float*)d_in[15];
    const float* g2We  = (const float*)d_in[16];
    const float* g2att = (const float*)d_in[17];
    const float* g2bias= (const float*)d_in[18];
    const float* ln2g  = (const float*)d_in[19];
    const float* ln2b  = (const float*)d_in[20];

    float* out = (float*)d_out;

    const int FUSED_BLOCKS = 4096;              // 16384 waves, ~25 edges each
    const int NW  = FUSED_BLOCKS * 4;
    const int CPE = (EE + NW - 1) / NW;

    // workspace layout (4-byte units)
    float* ws = (float*)d_ws;
    size_t o = 0;
    float* xl     = ws + o;         o += 12800000;   // N*256
    float* xr     = ws + o;         o += 12800000;   // N*256
    float* x1     = ws + o;         o += 3200000;    // N*64
    int*   rowptr = (int*)(ws + o); o += 50004;      // N+1 (+3 pad)
    int*   deg    = (int*)(ws + o); o += 50000;
    int*   cursor = (int*)(ws + o); o += 50000;
    int*   bsum   = (int*)(ws + o); o += 256;
    int*   srcs   = (int*)(ws + o); o += 400016;     // E + 16 pad (prefetch)
    int*   wstart = (int*)(ws + o); o += NW + 8;     // wave node ranges
    float* ea_s   = ws + o;         o += 6400000;    // E*16, CSR-sorted

    const int GEMM_BLOCKS  = (NN + 31) / 32;    // 1563
    const int SCAN_BLOCKS  = (NN + 255) / 256;  // 196
    const int EDGE_BLOCKS  = (EE + 255) / 256;  // 1563
    const int WR_BLOCKS    = (NW + 1 + 255) / 256;

    // ----- CSR build (once; graph identical for both layers) -----
    fill_u32<<<256, 256, 0, stream>>>((unsigned*)deg, 0u, NN);
    hist_k<<<EDGE_BLOCKS, 256, 0, stream>>>(ei, deg);
    scan1_k<<<SCAN_BLOCKS, 256, 0, stream>>>(deg, rowptr, bsum);
    scan2_k<<<1, 256, 0, stream>>>(bsum, SCAN_BLOCKS);
    scan3_k<<<SCAN_BLOCKS, 256, 0, stream>>>(rowptr, bsum, cursor);
    wrange_k<<<WR_BLOCKS, 256, 0, stream>>>(rowptr, wstart, NW, CPE);
    scatter_k<<<EDGE_BLOCKS, 256, 0, stream>>>(ei, cursor, ea, srcs, ea_s);

    // ----- layer 1 -----
    gemm_node_lr<<<GEMM_BLOCKS, 256, 0, stream>>>(h, g1Wl, g1bl, g1Wr, g1br, xl, xr);
    fused_edge_node_k<<<FUSED_BLOCKS, 256, 0, stream>>>(wstart, rowptr, srcs, ea_s,
                                                        g1We, g1att, xl, xr,
                                                        g1bias, ln1g, ln1b,
                                                        h, x1, out, 0);

    // ----- layer 2 -----
    gemm_node_lr<<<GEMM_BLOCKS, 256, 0, stream>>>(x1, g2Wl, g2bl, g2Wr, g2br, xl, xr);
    fused_edge_node_k<<<FUSED_BLOCKS, 256, 0, stream>>>(wstart, rowptr, srcs, ea_s,
                                                        g2We, g2att, xl, xr,
                                                        g2bias, ln2g, ln2b,
                                                        h, x1, out, 1);
}